// Round 4
// baseline (162.654 us; speedup 1.0000x reference)
//
#include <hip/hip_runtime.h>

#define NB    2048
#define AMAX  64
#define EDIM  128
#define TOTAL 66560          // = 520 * 128
#define DHEAD 16
#define KVSTR 20
#define XSTR  129
#define LSTR  136            // LDS row stride in fp16 (128 + 8 pad)
#define WELEM 65536          // winh (49152) + woh (16384) halfs

typedef _Float16 f16x8 __attribute__((ext_vector_type(8)));
typedef _Float16 f16x4 __attribute__((ext_vector_type(4)));
typedef float    f32x4 __attribute__((ext_vector_type(4)));

// ---------------- prep: block 0 = exclusive scan of agents; blocks 1..64 convert
// win (49152 f32) and wout (16384 f32) into contiguous f16 wh[] ----------------
__global__ __launch_bounds__(256) void prep_kernel(const int* __restrict__ ag,
                                                   int* __restrict__ offs,
                                                   const float* __restrict__ win,
                                                   const float* __restrict__ wout,
                                                   _Float16* __restrict__ wh) {
    if (blockIdx.x == 0) {
        __shared__ int part[256];
        const int t = threadIdx.x;
        int loc[8];
        int s = 0;
#pragma unroll
        for (int i = 0; i < 8; ++i) { loc[i] = s; s += ag[t * 8 + i]; }
        part[t] = s;
        __syncthreads();
        for (int d = 1; d < 256; d <<= 1) {
            int v = (t >= d) ? part[t - d] : 0;
            __syncthreads();
            part[t] += v;
            __syncthreads();
        }
        const int base = (t == 0) ? 0 : part[t - 1];
#pragma unroll
        for (int i = 0; i < 8; ++i) offs[t * 8 + i] = base + loc[i];
    } else {
        // blocks 1..48 -> win, 49..64 -> wout (1024-elem chunks never straddle)
        const int base = (blockIdx.x - 1) * 1024 + threadIdx.x * 4;
        const float4 v = (base < 49152) ? *(const float4*)(win + base)
                                        : *(const float4*)(wout + (base - 49152));
        f16x4 h;
        h[0] = (_Float16)v.x; h[1] = (_Float16)v.y;
        h[2] = (_Float16)v.z; h[3] = (_Float16)v.w;
        *(f16x4*)(wh + base) = h;
    }
}

// ---------------- fully fused: QKV projection + flash attention + out-projection ----------------
// 1 sample per block, 4 waves; wave w owns heads {2w, 2w+1}.
// Heavy-first (LPT) blockIdx->sample mapping: n(b) = (7b mod 64)+1, so sample order
// by descending n is b = ((63-(i>>5))*55 mod 64) + 64*(i&31)  (55 = 7^-1 mod 64).
// No x LDS tile: each wave loads its x fragments straight from global (f32->f16,
// zero-guarded for rows >= n -> values identical to the staged path). LDS holds only
// the ctx exchange buffer (17.4 KB) so several blocks co-reside per CU.
__global__ __launch_bounds__(256, 3) void fused_attn_kernel(
    const float*    __restrict__ x,     // [TOTAL][128] f32
    const _Float16* __restrict__ winh,  // [384][128] f16
    const float*    __restrict__ bin,   // [384] f32
    const _Float16* __restrict__ woh,   // [128][128] f16
    const float*    __restrict__ bout,  // [128] f32
    const int*      __restrict__ ag,
    const int*      __restrict__ offs,
    float*          __restrict__ out)   // [TOTAL][128] f32
{
    __shared__ __align__(16) _Float16 ctxs[AMAX * LSTR];   // 17408 B

    const int i    = blockIdx.x;
    const int b    = (((63 - (i >> 5)) * 55) & 63) + ((i & 31) << 6);
    const int n    = ag[b];
    const int off  = offs[b];
    const int tid  = threadIdx.x;
    const int lane = tid & 63;
    const int wid  = __builtin_amdgcn_readfirstlane(tid >> 6);
    const int l15  = lane & 15;
    const int quad = lane >> 4;
    const int nt   = (n + 15) >> 4;

    f16x4 ctxf[2][4] = {};   // [head m][qtile]; elem r -> q=qt*16+quad*4+r, d=l15

#pragma unroll
    for (int m = 0; m < 2; ++m) {
        const int h = wid * 2 + m;

        // weight fragments (L1/L2-hot)
        f16x8 wq[4], wk[4], wv[4];
#pragma unroll
        for (int ks = 0; ks < 4; ++ks) {
            wq[ks] = *(const f16x8*)(winh + (size_t)(h * 16 + l15) * EDIM + ks * 32 + quad * 8);
            wk[ks] = *(const f16x8*)(winh + (size_t)(128 + h * 16 + l15) * EDIM + ks * 32 + quad * 8);
            wv[ks] = *(const f16x8*)(winh + (size_t)(256 + h * 16 + l15) * EDIM + ks * 32 + quad * 8);
        }
        const float4 bq = *(const float4*)(bin + h * 16 + quad * 4);
        const float4 bk = *(const float4*)(bin + 128 + h * 16 + quad * 4);
        const float  bv = bin[256 + h * 16 + l15];
        const float bqa[4] = {bq.x, bq.y, bq.z, bq.w};
        const float bka[4] = {bk.x, bk.y, bk.z, bk.w};

        // ---- QKV projection, x fragments straight from global ----
        f16x4 qf[4], kf[4], vf[4];
#pragma unroll
        for (int kt = 0; kt < 4; ++kt) if (kt < nt) {
            const int row = kt * 16 + l15;
            const bool rv = row < n;
            const float* xr = x + (size_t)(off + row) * EDIM;
            f16x8 xf[4];
#pragma unroll
            for (int ks = 0; ks < 4; ++ks) xf[ks] = (f16x8){};
            if (rv) {
#pragma unroll
                for (int ks = 0; ks < 4; ++ks) {
                    const float4 a0 = *(const float4*)(xr + ks * 32 + quad * 8);
                    const float4 a1 = *(const float4*)(xr + ks * 32 + quad * 8 + 4);
                    f16x8 hv;
                    hv[0]=(_Float16)a0.x; hv[1]=(_Float16)a0.y; hv[2]=(_Float16)a0.z; hv[3]=(_Float16)a0.w;
                    hv[4]=(_Float16)a1.x; hv[5]=(_Float16)a1.y; hv[6]=(_Float16)a1.z; hv[7]=(_Float16)a1.w;
                    xf[ks] = hv;
                }
            }
            f32x4 aq = (f32x4){0.f,0.f,0.f,0.f};
            f32x4 ak = (f32x4){0.f,0.f,0.f,0.f};
            f32x4 av = (f32x4){0.f,0.f,0.f,0.f};
#pragma unroll
            for (int ks = 0; ks < 4; ++ks) {
                aq = __builtin_amdgcn_mfma_f32_16x16x32_f16(wq[ks], xf[ks], aq, 0, 0, 0);
                ak = __builtin_amdgcn_mfma_f32_16x16x32_f16(wk[ks], xf[ks], ak, 0, 0, 0);
                av = __builtin_amdgcn_mfma_f32_16x16x32_f16(xf[ks], wv[ks], av, 0, 0, 0);
            }
#pragma unroll
            for (int r = 0; r < 4; ++r) {
                qf[kt][r] = (_Float16)((aq[r] + bqa[r]) * 0.25f);   // 1/sqrt(16)
                kf[kt][r] = (_Float16)(ak[r] + bka[r]);
                vf[kt][r] = (_Float16)(av[r] + bv);
            }
        }

        // ---- attention (all-register; 2 shuffles per q-tile) ----
#pragma unroll
        for (int qt = 0; qt < 4; ++qt) if (qt < nt) {
            f32x4 sv[4];
#pragma unroll
            for (int kt = 0; kt < 4; ++kt) if (kt < nt)
                sv[kt] = __builtin_amdgcn_mfma_f32_16x16x16f16(
                             kf[kt], qf[qt], (f32x4){0.f,0.f,0.f,0.f}, 0, 0, 0);
            float ls = 0.f;
#pragma unroll
            for (int kt = 0; kt < 4; ++kt) if (kt < nt) {
#pragma unroll
                for (int r = 0; r < 4; ++r) {
                    const int key = kt * 16 + quad * 4 + r;
                    const float p = (key < n) ? __expf(sv[kt][r]) : 0.f;
                    ls += p;
                    sv[kt][r] = p;
                }
            }
            ls += __shfl_xor(ls, 16, 64);
            ls += __shfl_xor(ls, 32, 64);
            const float inv = 1.0f / ls;
            f16x4 pf[4];
#pragma unroll
            for (int kt = 0; kt < 4; ++kt) if (kt < nt) {
#pragma unroll
                for (int r = 0; r < 4; ++r) pf[kt][r] = (_Float16)(sv[kt][r] * inv);
            }
            f32x4 acc = (f32x4){0.f,0.f,0.f,0.f};
#pragma unroll
            for (int kt = 0; kt < 4; ++kt) if (kt < nt)
                acc = __builtin_amdgcn_mfma_f32_16x16x16f16(pf[kt], vf[kt], acc, 0, 0, 0);
#pragma unroll
            for (int r = 0; r < 4; ++r)
                ctxf[m][qt][r] = (_Float16)acc[r];
        }
    }

    // ---- ctx -> LDS ----
#pragma unroll
    for (int m = 0; m < 2; ++m) {
        const int h = wid * 2 + m;
#pragma unroll
        for (int qt = 0; qt < 4; ++qt) if (qt < nt) {
#pragma unroll
            for (int r = 0; r < 4; ++r)
                ctxs[(qt * 16 + quad * 4 + r) * LSTR + h * 16 + l15] = ctxf[m][qt][r];
        }
    }
    __syncthreads();

    // ---- out-projection: wave w handles row-tile w (16 rows); cols = all 128 ----
    if (wid < nt) {
        f32x4 acc[8];
#pragma unroll
        for (int c = 0; c < 8; ++c) acc[c] = (f32x4){0.f,0.f,0.f,0.f};
#pragma unroll
        for (int ks = 0; ks < 4; ++ks) {
            const f16x8 rfrag = *(const f16x8*)(ctxs + (wid * 16 + l15) * LSTR + ks * 32 + quad * 8);
            f16x8 cf[8];
#pragma unroll
            for (int c = 0; c < 8; ++c)
                cf[c] = *(const f16x8*)(woh + (c * 16 + l15) * EDIM + ks * 32 + quad * 8);
#pragma unroll
            for (int c = 0; c < 8; ++c)
                acc[c] = __builtin_amdgcn_mfma_f32_16x16x32_f16(cf[c], rfrag, acc[c], 0, 0, 0);
        }
        const int row = wid * 16 + l15;
        if (row < n) {
            float* orow = out + (size_t)(off + row) * EDIM;
#pragma unroll
            for (int c = 0; c < 8; ++c) {
                const int col = c * 16 + quad * 4;
                const float4 bvv = *(const float4*)(bout + col);
                *(float4*)(orow + col) =
                    make_float4(acc[c][0] + bvv.x, acc[c][1] + bvv.y,
                                acc[c][2] + bvv.z, acc[c][3] + bvv.w);
            }
        }
    }
}

// ================= fallback: fused fp32 kernel (used if ws too small) =================
__global__ __launch_bounds__(256, 2) void attn_fused_kernel(
    const float* __restrict__ x, const float* __restrict__ win,
    const float* __restrict__ bin, const float* __restrict__ wout,
    const float* __restrict__ bout, const int* __restrict__ ag,
    const int* __restrict__ offs, float* __restrict__ out)
{
    __shared__ __align__(16) float xs[AMAX * XSTR];
    __shared__ __align__(16) float kvs[8][AMAX * KVSTR];
    const int b = blockIdx.x, n = ag[b], off = offs[b];
    const int tid = threadIdx.x, lane = tid & 63;
    const int wid = __builtin_amdgcn_readfirstlane(tid >> 6);
#pragma unroll
    for (int it = 0; it < 8; ++it) {
        const int f4 = it * 256 + tid;
        const int r = f4 >> 5, c = (f4 & 31) << 2;
        float4 v = make_float4(0.f, 0.f, 0.f, 0.f);
        if (r < n) v = *(const float4*)(x + (size_t)(off + r) * EDIM + c);
        float* d = xs + r * XSTR + c;
        d[0]=v.x; d[1]=v.y; d[2]=v.z; d[3]=v.w;
    }
    __syncthreads();
    float* kw = kvs[wid*2+0]; float* vw = kvs[wid*2+1];
    const float* xrow = xs + lane * XSTR;
    float ctxk[2][DHEAD];
#pragma unroll
    for (int m = 0; m < 2; ++m) {
        const int h = wid * 2 + m;
        float qa[DHEAD], ka[DHEAD], va[DHEAD];
#pragma unroll
        for (int d = 0; d < DHEAD; ++d) { qa[d]=0.f; ka[d]=0.f; va[d]=0.f; }
        const float* wq = win + (size_t)(h*DHEAD)*EDIM;
        const float* wk = win + (size_t)(EDIM + h*DHEAD)*EDIM;
        const float* wv = win + (size_t)(2*EDIM + h*DHEAD)*EDIM;
        for (int k = 0; k < EDIM; ++k) {
            const float xv = xrow[k];
#pragma unroll
            for (int d = 0; d < DHEAD; ++d) {
                qa[d] = fmaf(xv, wq[d*EDIM+k], qa[d]);
                ka[d] = fmaf(xv, wk[d*EDIM+k], ka[d]);
                va[d] = fmaf(xv, wv[d*EDIM+k], va[d]);
            }
        }
#pragma unroll
        for (int d = 0; d < DHEAD; ++d) {
            qa[d] = (qa[d] + bin[h*DHEAD+d]) * 0.25f;
            ka[d] += bin[EDIM + h*DHEAD + d];
            va[d] += bin[2*EDIM + h*DHEAD + d];
        }
#pragma unroll
        for (int d = 0; d < DHEAD; ++d) { kw[lane*KVSTR+d] = ka[d]; vw[lane*KVSTR+d] = va[d]; }
        float mrun = -1e30f, lrun = 0.f, cacc[DHEAD];
#pragma unroll
        for (int d = 0; d < DHEAD; ++d) cacc[d] = 0.f;
        const int nch = (n + 15) >> 4;
        for (int ch = 0; ch < nch; ++ch) {
            const int jb = ch << 4;
            float s[16], p[16];
#pragma unroll
            for (int jj = 0; jj < 16; ++jj) {
                const float4* kr = (const float4*)(kw + (jb + jj) * KVSTR);
                const float4 k0=kr[0],k1=kr[1],k2=kr[2],k3=kr[3];
                const float kk[16] = {k0.x,k0.y,k0.z,k0.w,k1.x,k1.y,k1.z,k1.w,
                                      k2.x,k2.y,k2.z,k2.w,k3.x,k3.y,k3.z,k3.w};
                float a = 0.f;
#pragma unroll
                for (int d = 0; d < DHEAD; ++d) a = fmaf(qa[d], kk[d], a);
                s[jj] = (jb + jj < n) ? a : -1e30f;
            }
            float mc = s[0];
#pragma unroll
            for (int jj = 1; jj < 16; ++jj) mc = fmaxf(mc, s[jj]);
            const float mnew = fmaxf(mrun, mc);
            const float alpha = __expf(mrun - mnew);
            float psum = 0.f;
#pragma unroll
            for (int jj = 0; jj < 16; ++jj) { p[jj] = __expf(s[jj]-mnew); psum += p[jj]; }
            lrun = fmaf(lrun, alpha, psum);
#pragma unroll
            for (int d = 0; d < DHEAD; ++d) cacc[d] *= alpha;
#pragma unroll
            for (int jj = 0; jj < 16; ++jj) {
                const float4* vr = (const float4*)(vw + (jb + jj) * KVSTR);
                const float4 v0=vr[0],v1=vr[1],v2=vr[2],v3=vr[3];
                const float vv[16] = {v0.x,v0.y,v0.z,v0.w,v1.x,v1.y,v1.z,v1.w,
                                      v2.x,v2.y,v2.z,v2.w,v3.x,v3.y,v3.z,v3.w};
                const float pj = p[jj];
#pragma unroll
                for (int d = 0; d < DHEAD; ++d) cacc[d] = fmaf(pj, vv[d], cacc[d]);
            }
            mrun = mnew;
        }
        const float inv = 1.0f / lrun;
#pragma unroll
        for (int d = 0; d < DHEAD; ++d) ctxk[m][d] = cacc[d] * inv;
    }
    __syncthreads();
#pragma unroll
    for (int m = 0; m < 2; ++m) {
        const int h = wid * 2 + m;
#pragma unroll
        for (int d = 0; d < DHEAD; ++d) xs[lane*XSTR + h*DHEAD + d] = ctxk[m][d];
    }
    __syncthreads();
    const int c0 = wid * 32;
#pragma unroll
    for (int ct = 0; ct < 4; ++ct) {
        const int cc = c0 + ct * 8;
        float a8[8];
#pragma unroll
        for (int j = 0; j < 8; ++j) a8[j] = 0.f;
#pragma unroll 4
        for (int e = 0; e < EDIM; ++e) {
            const float cv = xrow[e];
#pragma unroll
            for (int j = 0; j < 8; ++j) a8[j] = fmaf(cv, wout[(size_t)(cc+j)*EDIM+e], a8[j]);
        }
        if (lane < n) {
            float* orow = out + (size_t)(off + lane) * EDIM + cc;
#pragma unroll
            for (int j = 0; j < 8; ++j) orow[j] = a8[j] + bout[cc+j];
        }
    }
}

extern "C" void kernel_launch(void* const* d_in, const int* in_sizes, int n_in,
                              void* d_out, int out_size, void* d_ws, size_t ws_size,
                              hipStream_t stream) {
    const float* x   = (const float*)d_in[0];
    const float* win = (const float*)d_in[1];
    const float* bin = (const float*)d_in[2];
    const float* wo  = (const float*)d_in[3];
    const float* bo  = (const float*)d_in[4];
    const int*   ag  = (const int*)d_in[5];
    float* out = (float*)d_out;

    // ws layout: winh [49152] f16 | woh [16384] f16 | offs [NB] int
    const size_t need = (size_t)WELEM * sizeof(_Float16) + NB * sizeof(int);
    if (ws_size >= need) {
        _Float16* wh = (_Float16*)d_ws;
        int* offs = (int*)(wh + WELEM);
        prep_kernel<<<65, 256, 0, stream>>>(ag, offs, win, wo, wh);
        fused_attn_kernel<<<NB, 256, 0, stream>>>(x, wh, bin, wh + 49152, bo, ag, offs, out);
    } else {
        int* offs = (int*)d_ws;
        prep_kernel<<<1, 256, 0, stream>>>(ag, offs, nullptr, nullptr, nullptr);
        attn_fused_kernel<<<NB, 256, 0, stream>>>(x, win, bin, wo, bo, ag, offs, out);
    }
}

// Round 5
// 141.327 us; speedup vs baseline: 1.1509x; 1.1509x over previous
//
#include <hip/hip_runtime.h>

#define NB    2048
#define AMAX  64
#define EDIM  128
#define TOTAL 66560          // = 520 * 128
#define DHEAD 16
#define KVSTR 20
#define XSTR  129
#define LSTR  136            // LDS row stride in fp16 (128 + 8 pad)
#define WELEM 65536          // winh (49152) + woh (16384) halfs

typedef _Float16 f16x8 __attribute__((ext_vector_type(8)));
typedef _Float16 f16x4 __attribute__((ext_vector_type(4)));
typedef float    f32x4 __attribute__((ext_vector_type(4)));

// ---------------- prep: block 0 = exclusive scan of agents; blocks 1..64 convert
// win (49152 f32) and wout (16384 f32) into contiguous f16 wh[] ----------------
__global__ __launch_bounds__(256) void prep_kernel(const int* __restrict__ ag,
                                                   int* __restrict__ offs,
                                                   const float* __restrict__ win,
                                                   const float* __restrict__ wout,
                                                   _Float16* __restrict__ wh) {
    if (blockIdx.x == 0) {
        __shared__ int part[256];
        const int t = threadIdx.x;
        int loc[8];
        int s = 0;
#pragma unroll
        for (int i = 0; i < 8; ++i) { loc[i] = s; s += ag[t * 8 + i]; }
        part[t] = s;
        __syncthreads();
        for (int d = 1; d < 256; d <<= 1) {
            int v = (t >= d) ? part[t - d] : 0;
            __syncthreads();
            part[t] += v;
            __syncthreads();
        }
        const int base = (t == 0) ? 0 : part[t - 1];
#pragma unroll
        for (int i = 0; i < 8; ++i) offs[t * 8 + i] = base + loc[i];
    } else {
        // blocks 1..48 -> win, 49..64 -> wout (1024-elem chunks never straddle)
        const int base = (blockIdx.x - 1) * 1024 + threadIdx.x * 4;
        const float4 v = (base < 49152) ? *(const float4*)(win + base)
                                        : *(const float4*)(wout + (base - 49152));
        f16x4 h;
        h[0] = (_Float16)v.x; h[1] = (_Float16)v.y;
        h[2] = (_Float16)v.z; h[3] = (_Float16)v.w;
        *(f16x4*)(wh + base) = h;
    }
}

// ---------------- fully fused: QKV projection + flash attention + out-projection ----------------
// 1 sample per block (LPT heavy-first mapping), 4 waves; wave w owns heads {2w, 2w+1},
// processed INTERLEAVED (not serially): both heads' weights hoisted, proj reads each
// x fragment once and feeds 6 independent MFMA chains; attention runs both heads'
// QK/softmax/PV as two independent dataflow chains. PV uses a split accumulator.
// Out-projection is column-split (wave w -> cols [32w,32w+32) for ALL row tiles) so
// all 4 waves stay active for any n. x is LDS-staged once per block (r2-proven);
// the same buffer is reused for the ctx exchange after a barrier.
__global__ __launch_bounds__(256, 2) void fused_attn_kernel(
    const float*    __restrict__ x,     // [TOTAL][128] f32
    const _Float16* __restrict__ winh,  // [384][128] f16
    const float*    __restrict__ bin,   // [384] f32
    const _Float16* __restrict__ woh,   // [128][128] f16
    const float*    __restrict__ bout,  // [128] f32
    const int*      __restrict__ ag,
    const int*      __restrict__ offs,
    float*          __restrict__ out)   // [TOTAL][128] f32
{
    __shared__ __align__(16) _Float16 xs[AMAX * LSTR];   // 17408 B; x tile, then ctx

    const int i    = blockIdx.x;
    const int b    = (((63 - (i >> 5)) * 55) & 63) + ((i & 31) << 6);
    const int n    = ag[b];
    const int off  = offs[b];
    const int tid  = threadIdx.x;
    const int lane = tid & 63;
    const int wid  = __builtin_amdgcn_readfirstlane(tid >> 6);
    const int l15  = lane & 15;
    const int quad = lane >> 4;
    const int nt   = (n + 15) >> 4;

    // ---- stage x -> xs (f16), zero-fill rows >= n ----
#pragma unroll
    for (int it = 0; it < 4; ++it) {
        const int u = it * 256 + tid;        // 1024 units of 8 halfs
        const int r = u >> 4, c8 = u & 15;
        f16x8 hv = {};
        if (r < n) {
            const float4 a0 = *(const float4*)(x + (size_t)(off + r) * EDIM + c8 * 8);
            const float4 a1 = *(const float4*)(x + (size_t)(off + r) * EDIM + c8 * 8 + 4);
            hv[0]=(_Float16)a0.x; hv[1]=(_Float16)a0.y; hv[2]=(_Float16)a0.z; hv[3]=(_Float16)a0.w;
            hv[4]=(_Float16)a1.x; hv[5]=(_Float16)a1.y; hv[6]=(_Float16)a1.z; hv[7]=(_Float16)a1.w;
        }
        *(f16x8*)(xs + r * LSTR + c8 * 8) = hv;
    }
    __syncthreads();

    // ---- hoist both heads' weight fragments + biases ----
    f16x8 wq[2][4], wk[2][4], wv[2][4];
    float bqa[2][4], bka[2][4], bva[2];
#pragma unroll
    for (int m = 0; m < 2; ++m) {
        const int h = wid * 2 + m;
#pragma unroll
        for (int ks = 0; ks < 4; ++ks) {
            wq[m][ks] = *(const f16x8*)(winh + (size_t)(h * 16 + l15) * EDIM + ks * 32 + quad * 8);
            wk[m][ks] = *(const f16x8*)(winh + (size_t)(128 + h * 16 + l15) * EDIM + ks * 32 + quad * 8);
            wv[m][ks] = *(const f16x8*)(winh + (size_t)(256 + h * 16 + l15) * EDIM + ks * 32 + quad * 8);
        }
        const float4 bq = *(const float4*)(bin + h * 16 + quad * 4);
        const float4 bk = *(const float4*)(bin + 128 + h * 16 + quad * 4);
        bqa[m][0]=bq.x; bqa[m][1]=bq.y; bqa[m][2]=bq.z; bqa[m][3]=bq.w;
        bka[m][0]=bk.x; bka[m][1]=bk.y; bka[m][2]=bk.z; bka[m][3]=bk.w;
        bva[m] = bin[256 + h * 16 + l15];
    }

    // ---- QKV projection: each xf read once, 6 independent MFMA chains ----
    f16x4 qf[2][4], kf[2][4], vf[2][4];
#pragma unroll
    for (int kt = 0; kt < 4; ++kt) if (kt < nt) {
        f16x8 xf[4];
#pragma unroll
        for (int ks = 0; ks < 4; ++ks)
            xf[ks] = *(const f16x8*)(xs + (kt * 16 + l15) * LSTR + ks * 32 + quad * 8);
#pragma unroll
        for (int m = 0; m < 2; ++m) {
            f32x4 aq = (f32x4){0.f,0.f,0.f,0.f};
            f32x4 ak = (f32x4){0.f,0.f,0.f,0.f};
            f32x4 av = (f32x4){0.f,0.f,0.f,0.f};
#pragma unroll
            for (int ks = 0; ks < 4; ++ks) {
                aq = __builtin_amdgcn_mfma_f32_16x16x32_f16(wq[m][ks], xf[ks], aq, 0, 0, 0);
                ak = __builtin_amdgcn_mfma_f32_16x16x32_f16(wk[m][ks], xf[ks], ak, 0, 0, 0);
                av = __builtin_amdgcn_mfma_f32_16x16x32_f16(xf[ks], wv[m][ks], av, 0, 0, 0);
            }
#pragma unroll
            for (int r = 0; r < 4; ++r) {
                qf[m][kt][r] = (_Float16)((aq[r] + bqa[m][r]) * 0.25f);   // 1/sqrt(16)
                kf[m][kt][r] = (_Float16)(ak[r] + bka[m][r]);
                vf[m][kt][r] = (_Float16)(av[r] + bva[m]);
            }
        }
    }

    // ---- attention: both heads interleaved; 2 shuffles per head per q-tile ----
    f16x4 ctxf[2][4] = {};   // [head m][qtile]; elem r -> q=qt*16+quad*4+r, d=l15
#pragma unroll
    for (int qt = 0; qt < 4; ++qt) if (qt < nt) {
        f32x4 sv0[4], sv1[4];
#pragma unroll
        for (int kt = 0; kt < 4; ++kt) if (kt < nt) {
            sv0[kt] = __builtin_amdgcn_mfma_f32_16x16x16f16(
                          kf[0][kt], qf[0][qt], (f32x4){0.f,0.f,0.f,0.f}, 0, 0, 0);
            sv1[kt] = __builtin_amdgcn_mfma_f32_16x16x16f16(
                          kf[1][kt], qf[1][qt], (f32x4){0.f,0.f,0.f,0.f}, 0, 0, 0);
        }
        float ls0 = 0.f, ls1 = 0.f;
#pragma unroll
        for (int kt = 0; kt < 4; ++kt) if (kt < nt) {
#pragma unroll
            for (int r = 0; r < 4; ++r) {
                const int key = kt * 16 + quad * 4 + r;
                const float p0 = (key < n) ? __expf(sv0[kt][r]) : 0.f;
                const float p1 = (key < n) ? __expf(sv1[kt][r]) : 0.f;
                ls0 += p0; sv0[kt][r] = p0;
                ls1 += p1; sv1[kt][r] = p1;
            }
        }
        ls0 += __shfl_xor(ls0, 16, 64);
        ls1 += __shfl_xor(ls1, 16, 64);
        ls0 += __shfl_xor(ls0, 32, 64);
        ls1 += __shfl_xor(ls1, 32, 64);
        const float inv0 = 1.0f / ls0;
        const float inv1 = 1.0f / ls1;
        f16x4 pf0[4], pf1[4];
#pragma unroll
        for (int kt = 0; kt < 4; ++kt) if (kt < nt) {
#pragma unroll
            for (int r = 0; r < 4; ++r) {
                pf0[kt][r] = (_Float16)(sv0[kt][r] * inv0);
                pf1[kt][r] = (_Float16)(sv1[kt][r] * inv1);
            }
        }
        // PV with split accumulators (even/odd kt), both heads independent
        f32x4 a0A = (f32x4){0.f,0.f,0.f,0.f}, a0B = (f32x4){0.f,0.f,0.f,0.f};
        f32x4 a1A = (f32x4){0.f,0.f,0.f,0.f}, a1B = (f32x4){0.f,0.f,0.f,0.f};
#pragma unroll
        for (int kt = 0; kt < 4; ++kt) if (kt < nt) {
            if ((kt & 1) == 0) {
                a0A = __builtin_amdgcn_mfma_f32_16x16x16f16(pf0[kt], vf[0][kt], a0A, 0, 0, 0);
                a1A = __builtin_amdgcn_mfma_f32_16x16x16f16(pf1[kt], vf[1][kt], a1A, 0, 0, 0);
            } else {
                a0B = __builtin_amdgcn_mfma_f32_16x16x16f16(pf0[kt], vf[0][kt], a0B, 0, 0, 0);
                a1B = __builtin_amdgcn_mfma_f32_16x16x16f16(pf1[kt], vf[1][kt], a1B, 0, 0, 0);
            }
        }
#pragma unroll
        for (int r = 0; r < 4; ++r) {
            ctxf[0][qt][r] = (_Float16)(a0A[r] + a0B[r]);
            ctxf[1][qt][r] = (_Float16)(a1A[r] + a1B[r]);
        }
    }

    // ---- ctx -> LDS (reuse xs; all proj reads of xs are done before this barrier) ----
    __syncthreads();
#pragma unroll
    for (int m = 0; m < 2; ++m) {
        const int h = wid * 2 + m;
#pragma unroll
        for (int qt = 0; qt < 4; ++qt) if (qt < nt) {
#pragma unroll
            for (int r = 0; r < 4; ++r)
                xs[(qt * 16 + quad * 4 + r) * LSTR + h * 16 + l15] = ctxf[m][qt][r];
        }
    }
    __syncthreads();

    // ---- out-projection, column-split: wave w -> cols [32w, 32w+32), all row tiles ----
    {
        f32x4 oacc[4][2];
#pragma unroll
        for (int t = 0; t < 4; ++t) { oacc[t][0] = (f32x4){0.f,0.f,0.f,0.f}; oacc[t][1] = (f32x4){0.f,0.f,0.f,0.f}; }
#pragma unroll
        for (int ks = 0; ks < 4; ++ks) {
            f16x8 cf[2];
#pragma unroll
            for (int c2 = 0; c2 < 2; ++c2)
                cf[c2] = *(const f16x8*)(woh + (wid * 32 + c2 * 16 + l15) * EDIM + ks * 32 + quad * 8);
#pragma unroll
            for (int t = 0; t < 4; ++t) if (t < nt) {
                const f16x8 rf = *(const f16x8*)(xs + (t * 16 + l15) * LSTR + ks * 32 + quad * 8);
                oacc[t][0] = __builtin_amdgcn_mfma_f32_16x16x32_f16(cf[0], rf, oacc[t][0], 0, 0, 0);
                oacc[t][1] = __builtin_amdgcn_mfma_f32_16x16x32_f16(cf[1], rf, oacc[t][1], 0, 0, 0);
            }
        }
        const float4 bo0 = *(const float4*)(bout + wid * 32 + quad * 4);
        const float4 bo1 = *(const float4*)(bout + wid * 32 + 16 + quad * 4);
#pragma unroll
        for (int t = 0; t < 4; ++t) if (t < nt) {
            const int row = t * 16 + l15;
            if (row < n) {
                float* orow = out + (size_t)(off + row) * EDIM + wid * 32;
                *(float4*)(orow + quad * 4) =
                    make_float4(oacc[t][0][0] + bo0.x, oacc[t][0][1] + bo0.y,
                                oacc[t][0][2] + bo0.z, oacc[t][0][3] + bo0.w);
                *(float4*)(orow + 16 + quad * 4) =
                    make_float4(oacc[t][1][0] + bo1.x, oacc[t][1][1] + bo1.y,
                                oacc[t][1][2] + bo1.z, oacc[t][1][3] + bo1.w);
            }
        }
    }
}

// ================= fallback: fused fp32 kernel (used if ws too small) =================
__global__ __launch_bounds__(256, 2) void attn_fused_kernel(
    const float* __restrict__ x, const float* __restrict__ win,
    const float* __restrict__ bin, const float* __restrict__ wout,
    const float* __restrict__ bout, const int* __restrict__ ag,
    const int* __restrict__ offs, float* __restrict__ out)
{
    __shared__ __align__(16) float xs[AMAX * XSTR];
    __shared__ __align__(16) float kvs[8][AMAX * KVSTR];
    const int b = blockIdx.x, n = ag[b], off = offs[b];
    const int tid = threadIdx.x, lane = tid & 63;
    const int wid = __builtin_amdgcn_readfirstlane(tid >> 6);
#pragma unroll
    for (int it = 0; it < 8; ++it) {
        const int f4 = it * 256 + tid;
        const int r = f4 >> 5, c = (f4 & 31) << 2;
        float4 v = make_float4(0.f, 0.f, 0.f, 0.f);
        if (r < n) v = *(const float4*)(x + (size_t)(off + r) * EDIM + c);
        float* d = xs + r * XSTR + c;
        d[0]=v.x; d[1]=v.y; d[2]=v.z; d[3]=v.w;
    }
    __syncthreads();
    float* kw = kvs[wid*2+0]; float* vw = kvs[wid*2+1];
    const float* xrow = xs + lane * XSTR;
    float ctxk[2][DHEAD];
#pragma unroll
    for (int m = 0; m < 2; ++m) {
        const int h = wid * 2 + m;
        float qa[DHEAD], ka[DHEAD], va[DHEAD];
#pragma unroll
        for (int d = 0; d < DHEAD; ++d) { qa[d]=0.f; ka[d]=0.f; va[d]=0.f; }
        const float* wq = win + (size_t)(h*DHEAD)*EDIM;
        const float* wk = win + (size_t)(EDIM + h*DHEAD)*EDIM;
        const float* wv = win + (size_t)(2*EDIM + h*DHEAD)*EDIM;
        for (int k = 0; k < EDIM; ++k) {
            const float xv = xrow[k];
#pragma unroll
            for (int d = 0; d < DHEAD; ++d) {
                qa[d] = fmaf(xv, wq[d*EDIM+k], qa[d]);
                ka[d] = fmaf(xv, wk[d*EDIM+k], ka[d]);
                va[d] = fmaf(xv, wv[d*EDIM+k], va[d]);
            }
        }
#pragma unroll
        for (int d = 0; d < DHEAD; ++d) {
            qa[d] = (qa[d] + bin[h*DHEAD+d]) * 0.25f;
            ka[d] += bin[EDIM + h*DHEAD + d];
            va[d] += bin[2*EDIM + h*DHEAD + d];
        }
#pragma unroll
        for (int d = 0; d < DHEAD; ++d) { kw[lane*KVSTR+d] = ka[d]; vw[lane*KVSTR+d] = va[d]; }
        float mrun = -1e30f, lrun = 0.f, cacc[DHEAD];
#pragma unroll
        for (int d = 0; d < DHEAD; ++d) cacc[d] = 0.f;
        const int nch = (n + 15) >> 4;
        for (int ch = 0; ch < nch; ++ch) {
            const int jb = ch << 4;
            float s[16], p[16];
#pragma unroll
            for (int jj = 0; jj < 16; ++jj) {
                const float4* kr = (const float4*)(kw + (jb + jj) * KVSTR);
                const float4 k0=kr[0],k1=kr[1],k2=kr[2],k3=kr[3];
                const float kk[16] = {k0.x,k0.y,k0.z,k0.w,k1.x,k1.y,k1.z,k1.w,
                                      k2.x,k2.y,k2.z,k2.w,k3.x,k3.y,k3.z,k3.w};
                float a = 0.f;
#pragma unroll
                for (int d = 0; d < DHEAD; ++d) a = fmaf(qa[d], kk[d], a);
                s[jj] = (jb + jj < n) ? a : -1e30f;
            }
            float mc = s[0];
#pragma unroll
            for (int jj = 1; jj < 16; ++jj) mc = fmaxf(mc, s[jj]);
            const float mnew = fmaxf(mrun, mc);
            const float alpha = __expf(mrun - mnew);
            float psum = 0.f;
#pragma unroll
            for (int jj = 0; jj < 16; ++jj) { p[jj] = __expf(s[jj]-mnew); psum += p[jj]; }
            lrun = fmaf(lrun, alpha, psum);
#pragma unroll
            for (int d = 0; d < DHEAD; ++d) cacc[d] *= alpha;
#pragma unroll
            for (int jj = 0; jj < 16; ++jj) {
                const float4* vr = (const float4*)(vw + (jb + jj) * KVSTR);
                const float4 v0=vr[0],v1=vr[1],v2=vr[2],v3=vr[3];
                const float vv[16] = {v0.x,v0.y,v0.z,v0.w,v1.x,v1.y,v1.z,v1.w,
                                      v2.x,v2.y,v2.z,v2.w,v3.x,v3.y,v3.z,v3.w};
                const float pj = p[jj];
#pragma unroll
                for (int d = 0; d < DHEAD; ++d) cacc[d] = fmaf(pj, vv[d], cacc[d]);
            }
            mrun = mnew;
        }
        const float inv = 1.0f / lrun;
#pragma unroll
        for (int d = 0; d < DHEAD; ++d) ctxk[m][d] = cacc[d] * inv;
    }
    __syncthreads();
#pragma unroll
    for (int m = 0; m < 2; ++m) {
        const int h = wid * 2 + m;
#pragma unroll
        for (int d = 0; d < DHEAD; ++d) xs[lane*XSTR + h*DHEAD + d] = ctxk[m][d];
    }
    __syncthreads();
    const int c0 = wid * 32;
#pragma unroll
    for (int ct = 0; ct < 4; ++ct) {
        const int cc = c0 + ct * 8;
        float a8[8];
#pragma unroll
        for (int j = 0; j < 8; ++j) a8[j] = 0.f;
#pragma unroll 4
        for (int e = 0; e < EDIM; ++e) {
            const float cv = xrow[e];
#pragma unroll
            for (int j = 0; j < 8; ++j) a8[j] = fmaf(cv, wout[(size_t)(cc+j)*EDIM+e], a8[j]);
        }
        if (lane < n) {
            float* orow = out + (size_t)(off + lane) * EDIM + cc;
#pragma unroll
            for (int j = 0; j < 8; ++j) orow[j] = a8[j] + bout[cc+j];
        }
    }
}

extern "C" void kernel_launch(void* const* d_in, const int* in_sizes, int n_in,
                              void* d_out, int out_size, void* d_ws, size_t ws_size,
                              hipStream_t stream) {
    const float* x   = (const float*)d_in[0];
    const float* win = (const float*)d_in[1];
    const float* bin = (const float*)d_in[2];
    const float* wo  = (const float*)d_in[3];
    const float* bo  = (const float*)d_in[4];
    const int*   ag  = (const int*)d_in[5];
    float* out = (float*)d_out;

    // ws layout: winh [49152] f16 | woh [16384] f16 | offs [NB] int
    const size_t need = (size_t)WELEM * sizeof(_Float16) + NB * sizeof(int);
    if (ws_size >= need) {
        _Float16* wh = (_Float16*)d_ws;
        int* offs = (int*)(wh + WELEM);
        prep_kernel<<<65, 256, 0, stream>>>(ag, offs, win, wo, wh);
        fused_attn_kernel<<<NB, 256, 0, stream>>>(x, wh, bin, wh + 49152, bo, ag, offs, out);
    } else {
        int* offs = (int*)d_ws;
        prep_kernel<<<1, 256, 0, stream>>>(ag, offs, nullptr, nullptr, nullptr);
        attn_fused_kernel<<<NB, 256, 0, stream>>>(x, win, bin, wo, bo, ag, offs, out);
    }
}